// Round 5
// baseline (3137.626 us; speedup 1.0000x reference)
//
#include <hip/hip_runtime.h>
#include <cstdint>

#define H_DIM 512
#define B_DIM 256
#define T_DIM 256

typedef __bf16 bf16x8 __attribute__((ext_vector_type(8)));
typedef __bf16 bf16x4 __attribute__((ext_vector_type(4)));
typedef float  f32x4  __attribute__((ext_vector_type(4)));
typedef unsigned long long ull;

__device__ __forceinline__ void cvt_split(float4 a, float4 b, bf16x8& h, bf16x8& lo) {
  const float v[8] = {a.x, a.y, a.z, a.w, b.x, b.y, b.z, b.w};
#pragma unroll
  for (int j = 0; j < 8; ++j) {
    h[j]  = (__bf16)v[j];
    lo[j] = (__bf16)(v[j] - (float)h[j]);
  }
}

// =====================================================================
// K1: Ux[(t*256+b)*512 + i] = sum_k x[b][t][k]*U[i][k] + bias[i]
// bf16 split-MFMA (xh@Uh + xh@Ul + xl@Uh ~ f32 accurate), f32 output.
// 128x128 tile, K-chunk 32, 256 threads (4 waves, 2x2), 80B-pad LDS rows.
// =====================================================================
__global__ __launch_bounds__(256, 2) void k1_ux(const float* __restrict__ x,
                                                const float* __restrict__ U,
                                                const float* __restrict__ bias,
                                                float* __restrict__ Ux) {
  __shared__ __align__(16) __bf16 XH[128][40];
  __shared__ __align__(16) __bf16 XL[128][40];
  __shared__ __align__(16) __bf16 UH[128][40];
  __shared__ __align__(16) __bf16 UL[128][40];

  const int tid = threadIdx.x;
  const int l   = tid & 63;
  const int w   = tid >> 6;
  const int wm  = w >> 1;
  const int wn  = w & 1;
  const int r0  = blockIdx.x * 128;   // rows (r = t*256 + b); 128 | 256 so one t
  const int i0  = blockIdx.y * 128;   // cols
  const int t   = r0 >> 8;
  const int b0  = r0 & 255;

  const int srow  = tid >> 1;         // staging: row 0..127
  const int shalf = tid & 1;          // staging: k-half (16 f32)

  f32x4 acc[4][4];
#pragma unroll
  for (int mi = 0; mi < 4; ++mi)
#pragma unroll
    for (int ni = 0; ni < 4; ++ni) acc[mi][ni] = (f32x4){0.f, 0.f, 0.f, 0.f};

  const int lrow = l & 15;            // frag row within 16
  const int lgrn = (l >> 4) * 8;      // frag k-offset (bf16)

  for (int k0 = 0; k0 < H_DIM; k0 += 32) {
    __syncthreads();
    // ---- stage x/U chunk -> hi/lo bf16 LDS ----
    {
      const float* xsrc = x + ((size_t)(b0 + srow) * T_DIM + t) * H_DIM + k0 + shalf * 16;
      const float* usrc = U + (size_t)(i0 + srow) * H_DIM + k0 + shalf * 16;
      bf16x8 h0, l0, h1, l1;
      cvt_split(*(const float4*)xsrc, *(const float4*)(xsrc + 4), h0, l0);
      cvt_split(*(const float4*)(xsrc + 8), *(const float4*)(xsrc + 12), h1, l1);
      *(bf16x8*)&XH[srow][shalf * 16]     = h0;
      *(bf16x8*)&XH[srow][shalf * 16 + 8] = h1;
      *(bf16x8*)&XL[srow][shalf * 16]     = l0;
      *(bf16x8*)&XL[srow][shalf * 16 + 8] = l1;
      cvt_split(*(const float4*)usrc, *(const float4*)(usrc + 4), h0, l0);
      cvt_split(*(const float4*)(usrc + 8), *(const float4*)(usrc + 12), h1, l1);
      *(bf16x8*)&UH[srow][shalf * 16]     = h0;
      *(bf16x8*)&UH[srow][shalf * 16 + 8] = h1;
      *(bf16x8*)&UL[srow][shalf * 16]     = l0;
      *(bf16x8*)&UL[srow][shalf * 16 + 8] = l1;
    }
    __syncthreads();

    // ---- frags + MFMA ----
    bf16x8 ah[4], al[4], bh[4], blo[4];
#pragma unroll
    for (int mi = 0; mi < 4; ++mi) {
      ah[mi] = *(const bf16x8*)&XH[wm * 64 + mi * 16 + lrow][lgrn];
      al[mi] = *(const bf16x8*)&XL[wm * 64 + mi * 16 + lrow][lgrn];
    }
#pragma unroll
    for (int ni = 0; ni < 4; ++ni) {
      bh[ni]  = *(const bf16x8*)&UH[wn * 64 + ni * 16 + lrow][lgrn];
      blo[ni] = *(const bf16x8*)&UL[wn * 64 + ni * 16 + lrow][lgrn];
    }
#pragma unroll
    for (int mi = 0; mi < 4; ++mi)
#pragma unroll
      for (int ni = 0; ni < 4; ++ni) {
        acc[mi][ni] = __builtin_amdgcn_mfma_f32_16x16x32_bf16(ah[mi], bh[ni],  acc[mi][ni], 0, 0, 0);
        acc[mi][ni] = __builtin_amdgcn_mfma_f32_16x16x32_bf16(ah[mi], blo[ni], acc[mi][ni], 0, 0, 0);
        acc[mi][ni] = __builtin_amdgcn_mfma_f32_16x16x32_bf16(al[mi], bh[ni],  acc[mi][ni], 0, 0, 0);
      }
  }

  // ---- epilogue: + bias, f32 store (C map: col=l&15, row=(l>>4)*4+r) ----
  float bv[4];
#pragma unroll
  for (int ni = 0; ni < 4; ++ni) bv[ni] = bias[i0 + wn * 64 + ni * 16 + lrow];
#pragma unroll
  for (int mi = 0; mi < 4; ++mi)
#pragma unroll
    for (int ni = 0; ni < 4; ++ni) {
      const int col = i0 + wn * 64 + ni * 16 + lrow;
      const int row = r0 + wm * 64 + mi * 16 + (l >> 4) * 4;
#pragma unroll
      for (int r = 0; r < 4; ++r)
        Ux[(size_t)(row + r) * H_DIM + col] = acc[mi][ni][r] + bv[ni];
    }
}

// =====================================================================
// K2: scan. 64 blocks x 512 threads. bid = slice*8 + g.
//   Per-wave dataflow sync: flags[g][slice][wave] (relaxed agent ops only).
//   A-frags loaded directly from ybuf (L3) per wave — no Y LDS stage.
//   One __syncthreads per step (Xex exchange); WAR on Xex protected by
//   the flag wait (own block's waves are among the polled peers).
// =====================================================================
__global__ __launch_bounds__(512, 1) void k2_scan(const float* __restrict__ W,
                                                  const float* __restrict__ Amat,
                                                  const float* __restrict__ y0,
                                                  const float* __restrict__ Ux,
                                                  const float* __restrict__ Wro,
                                                  __bf16* __restrict__ ybuf,      // 2*256*512 bf16
                                                  float* __restrict__ plog,       // [T][8][B]
                                                  unsigned int* __restrict__ flags) {  // [8][8][8]
  __shared__ float Xex[2][2][32][68];

  const int tid   = threadIdx.x;
  const int g     = blockIdx.x & 7;
  const int slice = blockIdx.x >> 3;
  const int fbase = slice * 64;

  const int l     = tid & 63;
  const int w     = tid >> 6;        // 0..7
  const int otype = w >> 2;          // 0 = pre (W), 1 = gate (A)
  const int ng    = (w >> 1) & 1;    // feature 32-group
  const int khalf = w & 1;           // K 256-split

  const int bl     = tid >> 4;       // batch-local 0..31
  const int f0i    = (tid & 15) * 4; // feature 0..60
  const int b_glob = g * 32 + bl;

  float4 yst = *(const float4*)(y0 + (size_t)b_glob * H_DIM + fbase + f0i);
  const float4 wrov = *(const float4*)(Wro + fbase + f0i);

  // ---- W/A fragments -> VGPRs (once) ----
  const int n0    = l & 15;
  const int kfrag = khalf * 256 + ((l >> 4) * 8);
  const float* Bsrc = otype ? Amat : W;
  bf16x8 bfr[2][8];
#pragma unroll
  for (int ks = 0; ks < 8; ++ks) {
#pragma unroll
    for (int h2 = 0; h2 < 2; ++h2) {
      const float* src = Bsrc + (size_t)(fbase + ng * 32 + n0 + h2 * 16) * H_DIM + kfrag + ks * 32;
      const float4 s0 = *(const float4*)src;
      const float4 s1 = *(const float4*)(src + 4);
      bf16x8 v;
      v[0] = (__bf16)s0.x; v[1] = (__bf16)s0.y; v[2] = (__bf16)s0.z; v[3] = (__bf16)s0.w;
      v[4] = (__bf16)s1.x; v[5] = (__bf16)s1.y; v[6] = (__bf16)s1.z; v[7] = (__bf16)s1.w;
      bfr[h2][ks] = v;
    }
  }

  const int ra0 = g * 32 + n0;       // global batch rows of A-frags
  const int ra1 = ra0 + 16;

  for (int t = 0; t < T_DIM; ++t) {
    const float4 uxv = *(const float4*)(Ux + ((size_t)t * B_DIM + b_glob) * H_DIM + fbase + f0i);

    // ---- wait: all 8 peer blocks x 8 waves published y_t (coalesced poll) ----
    if (t > 0) {
      const unsigned target = (unsigned)t;
      const unsigned int* fp = flags + g * 64 + l;
      for (;;) {
        const unsigned v = __hip_atomic_load(fp, __ATOMIC_RELAXED, __HIP_MEMORY_SCOPE_AGENT);
        if (__all(v >= target)) break;
        __builtin_amdgcn_s_sleep(1);
      }
      asm volatile("" ::: "memory");
    }

    // ---- A-frags direct (L3 for t>0; y0 f32 for t=0) ----
    bf16x8 a0[8], a1[8];
    if (t == 0) {
#pragma unroll
      for (int ks = 0; ks < 8; ++ks) {
        const float* p0 = y0 + (size_t)ra0 * H_DIM + kfrag + ks * 32;
        const float* p1 = y0 + (size_t)ra1 * H_DIM + kfrag + ks * 32;
        const float4 s0 = *(const float4*)p0, s1 = *(const float4*)(p0 + 4);
        const float4 u0 = *(const float4*)p1, u1 = *(const float4*)(p1 + 4);
        bf16x8 va, vb;
        va[0] = (__bf16)s0.x; va[1] = (__bf16)s0.y; va[2] = (__bf16)s0.z; va[3] = (__bf16)s0.w;
        va[4] = (__bf16)s1.x; va[5] = (__bf16)s1.y; va[6] = (__bf16)s1.z; va[7] = (__bf16)s1.w;
        vb[0] = (__bf16)u0.x; vb[1] = (__bf16)u0.y; vb[2] = (__bf16)u0.z; vb[3] = (__bf16)u0.w;
        vb[4] = (__bf16)u1.x; vb[5] = (__bf16)u1.y; vb[6] = (__bf16)u1.z; vb[7] = (__bf16)u1.w;
        a0[ks] = va; a1[ks] = vb;
      }
    } else {
      const ull* yc = (const ull*)(ybuf + (size_t)(t & 1) * (B_DIM * H_DIM));
#pragma unroll
      for (int ks = 0; ks < 8; ++ks) {
        const size_t i0q = ((size_t)ra0 * H_DIM + kfrag + ks * 32) >> 2;  // ull index
        const size_t i1q = ((size_t)ra1 * H_DIM + kfrag + ks * 32) >> 2;
        struct { ull a, b; } u0, u1;
        u0.a = __hip_atomic_load(yc + i0q,     __ATOMIC_RELAXED, __HIP_MEMORY_SCOPE_AGENT);
        u0.b = __hip_atomic_load(yc + i0q + 1, __ATOMIC_RELAXED, __HIP_MEMORY_SCOPE_AGENT);
        u1.a = __hip_atomic_load(yc + i1q,     __ATOMIC_RELAXED, __HIP_MEMORY_SCOPE_AGENT);
        u1.b = __hip_atomic_load(yc + i1q + 1, __ATOMIC_RELAXED, __HIP_MEMORY_SCOPE_AGENT);
        __builtin_memcpy(&a0[ks], &u0, 16);
        __builtin_memcpy(&a1[ks], &u1, 16);
      }
    }

    // ---- MFMA: 2M x 2N x 8K per wave ----
    f32x4 acc00 = {0.f, 0.f, 0.f, 0.f};
    f32x4 acc01 = {0.f, 0.f, 0.f, 0.f};
    f32x4 acc10 = {0.f, 0.f, 0.f, 0.f};
    f32x4 acc11 = {0.f, 0.f, 0.f, 0.f};
#pragma unroll
    for (int ks = 0; ks < 8; ++ks) {
      acc00 = __builtin_amdgcn_mfma_f32_16x16x32_bf16(a0[ks], bfr[0][ks], acc00, 0, 0, 0);
      acc01 = __builtin_amdgcn_mfma_f32_16x16x32_bf16(a0[ks], bfr[1][ks], acc01, 0, 0, 0);
      acc10 = __builtin_amdgcn_mfma_f32_16x16x32_bf16(a1[ks], bfr[0][ks], acc10, 0, 0, 0);
      acc11 = __builtin_amdgcn_mfma_f32_16x16x32_bf16(a1[ks], bfr[1][ks], acc11, 0, 0, 0);
    }

    // ---- partial-tile exchange ----
    {
      const int lr = (l >> 4) * 4;
      const int lc = l & 15;
#pragma unroll
      for (int r = 0; r < 4; ++r) {
        Xex[otype][khalf][lr + r][ng * 32 + lc]           = acc00[r];
        Xex[otype][khalf][lr + r][ng * 32 + lc + 16]      = acc01[r];
        Xex[otype][khalf][lr + r + 16][ng * 32 + lc]      = acc10[r];
        Xex[otype][khalf][lr + r + 16][ng * 32 + lc + 16] = acc11[r];
      }
    }
    __syncthreads();

    // ---- epilogue: combine, state update, publish (per-wave) ----
    {
      const float4 p0 = *(const float4*)&Xex[0][0][bl][f0i];
      const float4 p1 = *(const float4*)&Xex[0][1][bl][f0i];
      const float4 g0 = *(const float4*)&Xex[1][0][bl][f0i];
      const float4 g1 = *(const float4*)&Xex[1][1][bl][f0i];

      const float pr[4] = {p0.x + p1.x + uxv.x, p0.y + p1.y + uxv.y,
                           p0.z + p1.z + uxv.z, p0.w + p1.w + uxv.w};
      const float gv[4] = {g0.x + g1.x, g0.y + g1.y, g0.z + g1.z, g0.w + g1.w};
      const float yov[4] = {yst.x, yst.y, yst.z, yst.w};
      float yn[4];
#pragma unroll
      for (int j = 0; j < 4; ++j) {
        const float gate = 1.0f / (1.0f + expf(-gv[j]));
        yn[j] = yov[j] + 0.1f * tanhf(pr[j]) * gate;
      }
      yst.x = yn[0]; yst.y = yn[1]; yst.z = yn[2]; yst.w = yn[3];

      bf16x4 pk;
      pk[0] = (__bf16)yn[0]; pk[1] = (__bf16)yn[1];
      pk[2] = (__bf16)yn[2]; pk[3] = (__bf16)yn[3];
      ull pv;
      __builtin_memcpy(&pv, &pk, 8);
      ull* dst = (ull*)(ybuf + (size_t)((t + 1) & 1) * (B_DIM * H_DIM)
                        + (size_t)b_glob * H_DIM + fbase + f0i);
      __hip_atomic_store(dst, pv, __ATOMIC_RELAXED, __HIP_MEMORY_SCOPE_AGENT);

      float s = yn[0] * wrov.x + yn[1] * wrov.y + yn[2] * wrov.z + yn[3] * wrov.w;
      s += __shfl_xor(s, 1, 64);
      s += __shfl_xor(s, 2, 64);
      s += __shfl_xor(s, 4, 64);
      s += __shfl_xor(s, 8, 64);
      if ((tid & 15) == 0)
        plog[((size_t)t * 8 + slice) * B_DIM + b_glob] = s;
    }

    // ---- per-wave release: drain own stores, publish wave flag ----
    asm volatile("s_waitcnt vmcnt(0)" ::: "memory");
    if ((tid & 63) == 0)
      __hip_atomic_store(flags + g * 64 + slice * 8 + w, (unsigned)(t + 1),
                         __ATOMIC_RELAXED, __HIP_MEMORY_SCOPE_AGENT);
  }
}

// =====================================================================
// K3: out[b][t] = bro + sum_{s<8} plog[t][s][b]
// =====================================================================
__global__ __launch_bounds__(256) void k3_out(const float* __restrict__ plog,
                                              const float* __restrict__ bro,
                                              float* __restrict__ out) {
  const int t = blockIdx.x;
  const int b = threadIdx.x;
  float s = bro[0];
#pragma unroll
  for (int col = 0; col < 8; ++col)
    s += plog[((size_t)t * 8 + col) * B_DIM + b];
  out[(size_t)b * T_DIM + t] = s;
}

// =====================================================================
extern "C" void kernel_launch(void* const* d_in, const int* in_sizes, int n_in,
                              void* d_out, int out_size, void* d_ws, size_t ws_size,
                              hipStream_t stream) {
  const float* x   = (const float*)d_in[0];
  const float* y0  = (const float*)d_in[1];
  const float* W   = (const float*)d_in[2];
  const float* U   = (const float*)d_in[3];
  const float* b   = (const float*)d_in[4];
  const float* A   = (const float*)d_in[5];
  const float* Wro = (const float*)d_in[6];
  const float* bro = (const float*)d_in[7];
  float* out = (float*)d_out;

  float* ws = (float*)d_ws;
  float* Ux = ws;                                               // 33,554,432 f32
  __bf16* ybuf = (__bf16*)(ws + (size_t)T_DIM * B_DIM * H_DIM); // 262,144 bf16
  float* plog = ws + (size_t)T_DIM * B_DIM * H_DIM + 131072;    // 524,288 f32
  unsigned int* flags = (unsigned int*)(plog + (size_t)T_DIM * 8 * B_DIM);  // 512 u32

  (void)in_sizes; (void)n_in; (void)out_size; (void)ws_size;

  hipMemsetAsync(flags, 0, 512 * sizeof(unsigned int), stream);

  dim3 g1(512, 4);
  k1_ux<<<g1, 256, 0, stream>>>(x, U, b, Ux);
  k2_scan<<<64, 512, 0, stream>>>(W, A, y0, Ux, Wro, ybuf, plog, flags);
  k3_out<<<256, 256, 0, stream>>>(plog, bro, out);
}

// Round 6
// 1936.846 us; speedup vs baseline: 1.6200x; 1.6200x over previous
//
#include <hip/hip_runtime.h>
#include <cstdint>

#define H_DIM 512
#define B_DIM 256
#define T_DIM 256

typedef __bf16 bf16x8 __attribute__((ext_vector_type(8)));
typedef float  f32x4  __attribute__((ext_vector_type(4)));
typedef unsigned long long ull;

__device__ __forceinline__ void cvt_split(float4 a, float4 b, bf16x8& h, bf16x8& lo) {
  const float v[8] = {a.x, a.y, a.z, a.w, b.x, b.y, b.z, b.w};
#pragma unroll
  for (int j = 0; j < 8; ++j) {
    h[j]  = (__bf16)v[j];
    lo[j] = (__bf16)(v[j] - (float)h[j]);
  }
}

__device__ __forceinline__ bf16x8 cvt8(const float* p) {
  const float4 s0 = *(const float4*)p;
  const float4 s1 = *(const float4*)(p + 4);
  bf16x8 v;
  v[0] = (__bf16)s0.x; v[1] = (__bf16)s0.y; v[2] = (__bf16)s0.z; v[3] = (__bf16)s0.w;
  v[4] = (__bf16)s1.x; v[5] = (__bf16)s1.y; v[6] = (__bf16)s1.z; v[7] = (__bf16)s1.w;
  return v;
}

// =====================================================================
// K1: Ux[(t*256+b)*512 + i] = sum_k x[b][t][k]*U[i][k] + bias[i]
// bf16 split-MFMA (xh@Uh + xh@Ul + xl@Uh ~ f32 accurate), f32 output.
// =====================================================================
__global__ __launch_bounds__(256, 2) void k1_ux(const float* __restrict__ x,
                                                const float* __restrict__ U,
                                                const float* __restrict__ bias,
                                                float* __restrict__ Ux) {
  __shared__ __align__(16) __bf16 XH[128][40];
  __shared__ __align__(16) __bf16 XL[128][40];
  __shared__ __align__(16) __bf16 UH[128][40];
  __shared__ __align__(16) __bf16 UL[128][40];

  const int tid = threadIdx.x;
  const int l   = tid & 63;
  const int w   = tid >> 6;
  const int wm  = w >> 1;
  const int wn  = w & 1;
  const int r0  = blockIdx.x * 128;
  const int i0  = blockIdx.y * 128;
  const int t   = r0 >> 8;
  const int b0  = r0 & 255;

  const int srow  = tid >> 1;
  const int shalf = tid & 1;

  f32x4 acc[4][4];
#pragma unroll
  for (int mi = 0; mi < 4; ++mi)
#pragma unroll
    for (int ni = 0; ni < 4; ++ni) acc[mi][ni] = (f32x4){0.f, 0.f, 0.f, 0.f};

  const int lrow = l & 15;
  const int lgrn = (l >> 4) * 8;

  for (int k0 = 0; k0 < H_DIM; k0 += 32) {
    __syncthreads();
    {
      const float* xsrc = x + ((size_t)(b0 + srow) * T_DIM + t) * H_DIM + k0 + shalf * 16;
      const float* usrc = U + (size_t)(i0 + srow) * H_DIM + k0 + shalf * 16;
      bf16x8 h0, l0, h1, l1;
      cvt_split(*(const float4*)xsrc, *(const float4*)(xsrc + 4), h0, l0);
      cvt_split(*(const float4*)(xsrc + 8), *(const float4*)(xsrc + 12), h1, l1);
      *(bf16x8*)&XH[srow][shalf * 16]     = h0;
      *(bf16x8*)&XH[srow][shalf * 16 + 8] = h1;
      *(bf16x8*)&XL[srow][shalf * 16]     = l0;
      *(bf16x8*)&XL[srow][shalf * 16 + 8] = l1;
      cvt_split(*(const float4*)usrc, *(const float4*)(usrc + 4), h0, l0);
      cvt_split(*(const float4*)(usrc + 8), *(const float4*)(usrc + 12), h1, l1);
      *(bf16x8*)&UH[srow][shalf * 16]     = h0;
      *(bf16x8*)&UH[srow][shalf * 16 + 8] = h1;
      *(bf16x8*)&UL[srow][shalf * 16]     = l0;
      *(bf16x8*)&UL[srow][shalf * 16 + 8] = l1;
    }
    __syncthreads();

    bf16x8 ah[4], al[4], bh[4], blo[4];
#pragma unroll
    for (int mi = 0; mi < 4; ++mi) {
      ah[mi] = *(const bf16x8*)&XH[wm * 64 + mi * 16 + lrow][lgrn];
      al[mi] = *(const bf16x8*)&XL[wm * 64 + mi * 16 + lrow][lgrn];
    }
#pragma unroll
    for (int ni = 0; ni < 4; ++ni) {
      bh[ni]  = *(const bf16x8*)&UH[wn * 64 + ni * 16 + lrow][lgrn];
      blo[ni] = *(const bf16x8*)&UL[wn * 64 + ni * 16 + lrow][lgrn];
    }
#pragma unroll
    for (int mi = 0; mi < 4; ++mi)
#pragma unroll
      for (int ni = 0; ni < 4; ++ni) {
        acc[mi][ni] = __builtin_amdgcn_mfma_f32_16x16x32_bf16(ah[mi], bh[ni],  acc[mi][ni], 0, 0, 0);
        acc[mi][ni] = __builtin_amdgcn_mfma_f32_16x16x32_bf16(ah[mi], blo[ni], acc[mi][ni], 0, 0, 0);
        acc[mi][ni] = __builtin_amdgcn_mfma_f32_16x16x32_bf16(al[mi], bh[ni],  acc[mi][ni], 0, 0, 0);
      }
  }

  float bv[4];
#pragma unroll
  for (int ni = 0; ni < 4; ++ni) bv[ni] = bias[i0 + wn * 64 + ni * 16 + lrow];
#pragma unroll
  for (int mi = 0; mi < 4; ++mi)
#pragma unroll
    for (int ni = 0; ni < 4; ++ni) {
      const int col = i0 + wn * 64 + ni * 16 + lrow;
      const int row = r0 + wm * 64 + mi * 16 + (l >> 4) * 4;
#pragma unroll
      for (int r = 0; r < 4; ++r)
        Ux[(size_t)(row + r) * H_DIM + col] = acc[mi][ni][r] + bv[ni];
    }
}

// =====================================================================
// K2: scan. 64 blocks x 512 threads. bid = slice*8 + g.
//   Fully wave-autonomous: no LDS, no __syncthreads in the step loop.
//   ybuf is stored in MFMA-FRAGMENT ORDER per 16-batch tile:
//     elem (row, k) at byte tix*16384 + ks*1024 + (kc*16+row)*16 + j*2
//     (k = ks*32 + kc*8 + j) -> consumer frag load = 16B @ base + ks*1024
//     + l*16: 64 lanes perfectly contiguous (1 KB per frag).
//   Wave (bh, fq) owns a 16b x 16f tile, computes BOTH pre (W) and gate (A)
//   with full K=512 -> same lane/reg holds (pre,gate) for one (b,f):
//   pure-register epilogue. Sync: per-wave monotone flag, relaxed agent ops.
// =====================================================================
__global__ __launch_bounds__(512, 1) void k2_scan(const float* __restrict__ W,
                                                  const float* __restrict__ Amat,
                                                  const float* __restrict__ y0,
                                                  const float* __restrict__ Ux,
                                                  const float* __restrict__ Wro,
                                                  __bf16* __restrict__ ybuf,      // 2 x 131072 bf16 (frag order)
                                                  float* __restrict__ plog,       // [T][32][B]
                                                  unsigned int* __restrict__ flags) {  // [8][64]
  const int tid   = threadIdx.x;
  const int g     = blockIdx.x & 7;
  const int slice = blockIdx.x >> 3;
  const int fbase = slice * 64;

  const int l   = tid & 63;
  const int w   = tid >> 6;      // 0..7
  const int bh  = w & 1;         // batch half (16)
  const int fq  = w >> 1;        // feature quarter (16) within 64-slice
  const int l15 = l & 15;
  const int lhi = l >> 4;

  const int fglob = fbase + fq * 16 + l15;          // this lane's feature
  const int bbase = g * 32 + bh * 16 + lhi * 4;     // this lane's 4 batches

  // ---- own f32 state + readout weight ----
  float yst[4];
#pragma unroll
  for (int r = 0; r < 4; ++r)
    yst[r] = y0[(size_t)(bbase + r) * H_DIM + fglob];
  const float wro_s = Wro[fglob];

  // ---- B-frags (W and A rows = this lane's feature), VGPR resident ----
  bf16x8 bW[16], bA[16];
#pragma unroll
  for (int ks = 0; ks < 16; ++ks) {
    bW[ks] = cvt8(W    + (size_t)fglob * H_DIM + lhi * 8 + ks * 32);
    bA[ks] = cvt8(Amat + (size_t)fglob * H_DIM + lhi * 8 + ks * 32);
  }

  // ---- frag-layout addressing constants ----
  const size_t tix = (size_t)(g * 2 + bh);          // 16-batch tile index
  const int ksw = slice * 2 + (fq >> 1);            // store: k-super (per wave)
  const int kcw = (fq & 1) * 2 + ((l >> 3) & 1);    // store: k-chunk
  const int jof = (l & 7) * 2;                      // store: byte within 16B

  for (int t = 0; t < T_DIM; ++t) {
    // input-path term: issue before the wait (latency hides under it)
    float uxv[4];
#pragma unroll
    for (int r = 0; r < 4; ++r)
      uxv[r] = Ux[((size_t)t * B_DIM + bbase + r) * H_DIM + fglob];

    // ---- wait: all 64 waves of this group published y_t ----
    if (t > 0) {
      const unsigned target = (unsigned)t;
      const unsigned int* fp = flags + g * 64 + l;
      for (;;) {
        const unsigned v = __hip_atomic_load(fp, __ATOMIC_RELAXED, __HIP_MEMORY_SCOPE_AGENT);
        if (__all(v >= target)) break;
        __builtin_amdgcn_s_sleep(1);
      }
      asm volatile("" ::: "memory");
    }

    // ---- A-frags: coalesced L3 loads (frag-order ybuf), or y0 at t=0 ----
    bf16x8 av[16];
    if (t == 0) {
      const float* pa = y0 + (size_t)(g * 32 + bh * 16 + l15) * H_DIM + lhi * 8;
#pragma unroll
      for (int ks = 0; ks < 16; ++ks) av[ks] = cvt8(pa + ks * 32);
    } else {
      const char* abase = (const char*)ybuf + (size_t)(t & 1) * 262144
                        + tix * 16384 + (size_t)l * 16;
#pragma unroll
      for (int ks = 0; ks < 16; ++ks) {
        ull u2[2];
        u2[0] = __hip_atomic_load((const ull*)(abase + ks * 1024),
                                  __ATOMIC_RELAXED, __HIP_MEMORY_SCOPE_AGENT);
        u2[1] = __hip_atomic_load((const ull*)(abase + ks * 1024 + 8),
                                  __ATOMIC_RELAXED, __HIP_MEMORY_SCOPE_AGENT);
        __builtin_memcpy(&av[ks], u2, 16);
      }
    }

    // ---- MFMA: both matvecs for the same 16x16 tile, K=512 ----
    f32x4 accP = {0.f, 0.f, 0.f, 0.f};
    f32x4 accG = {0.f, 0.f, 0.f, 0.f};
#pragma unroll
    for (int ks = 0; ks < 16; ++ks) {
      accP = __builtin_amdgcn_mfma_f32_16x16x32_bf16(av[ks], bW[ks], accP, 0, 0, 0);
      accG = __builtin_amdgcn_mfma_f32_16x16x32_bf16(av[ks], bA[ks], accG, 0, 0, 0);
    }

    // ---- pure-register epilogue ----
    char* obase = (char*)ybuf + (size_t)((t + 1) & 1) * 262144 + tix * 16384
                + (size_t)ksw * 1024 + (size_t)(kcw * 16) * 16 + jof;
    float s[4];
#pragma unroll
    for (int r = 0; r < 4; ++r) {
      const float pre  = accP[r] + uxv[r];
      const float gate = 1.0f / (1.0f + expf(-accG[r]));
      const float yn   = yst[r] + 0.1f * tanhf(pre) * gate;
      yst[r] = yn;
      const __bf16 hb = (__bf16)yn;
      unsigned short hv;
      __builtin_memcpy(&hv, &hb, 2);
      __hip_atomic_store((unsigned short*)(obase + (lhi * 4 + r) * 16), hv,
                         __ATOMIC_RELAXED, __HIP_MEMORY_SCOPE_AGENT);
      s[r] = yn * wro_s;
    }

    // readout partial: reduce over the 16 feature-lanes
#pragma unroll
    for (int d = 1; d < 16; d <<= 1) {
#pragma unroll
      for (int r = 0; r < 4; ++r) s[r] += __shfl_xor(s[r], d, 64);
    }
    if (l15 == 0) {
      float4 sv; sv.x = s[0]; sv.y = s[1]; sv.z = s[2]; sv.w = s[3];
      *(float4*)(plog + ((size_t)t * 32 + slice * 4 + fq) * B_DIM + bbase) = sv;
    }

    // ---- per-wave release: drain own stores, publish wave flag ----
    asm volatile("s_waitcnt vmcnt(0)" ::: "memory");
    if (l == 0)
      __hip_atomic_store(flags + g * 64 + slice * 8 + w, (unsigned)(t + 1),
                         __ATOMIC_RELAXED, __HIP_MEMORY_SCOPE_AGENT);
  }
}

// =====================================================================
// K3: out[b][t] = bro + sum_{c<32} plog[t][c][b]
// =====================================================================
__global__ __launch_bounds__(256) void k3_out(const float* __restrict__ plog,
                                              const float* __restrict__ bro,
                                              float* __restrict__ out) {
  const int t = blockIdx.x;
  const int b = threadIdx.x;
  float s = bro[0];
#pragma unroll
  for (int col = 0; col < 32; ++col)
    s += plog[((size_t)t * 32 + col) * B_DIM + b];
  out[(size_t)b * T_DIM + t] = s;
}

// =====================================================================
extern "C" void kernel_launch(void* const* d_in, const int* in_sizes, int n_in,
                              void* d_out, int out_size, void* d_ws, size_t ws_size,
                              hipStream_t stream) {
  const float* x   = (const float*)d_in[0];
  const float* y0  = (const float*)d_in[1];
  const float* W   = (const float*)d_in[2];
  const float* U   = (const float*)d_in[3];
  const float* b   = (const float*)d_in[4];
  const float* A   = (const float*)d_in[5];
  const float* Wro = (const float*)d_in[6];
  const float* bro = (const float*)d_in[7];
  float* out = (float*)d_out;

  float* ws = (float*)d_ws;
  float* Ux = ws;                                               // 33,554,432 f32
  __bf16* ybuf = (__bf16*)(ws + (size_t)T_DIM * B_DIM * H_DIM); // 262,144 bf16 (frag order)
  float* plog = ws + (size_t)T_DIM * B_DIM * H_DIM + 131072;    // 2,097,152 f32
  unsigned int* flags = (unsigned int*)(plog + (size_t)T_DIM * 32 * B_DIM);  // 512 u32

  (void)in_sizes; (void)n_in; (void)out_size; (void)ws_size;

  hipMemsetAsync(flags, 0, 512 * sizeof(unsigned int), stream);

  dim3 g1(512, 4);
  k1_ux<<<g1, 256, 0, stream>>>(x, U, b, Ux);
  k2_scan<<<64, 512, 0, stream>>>(W, A, y0, Ux, Wro, ybuf, plog, flags);
  k3_out<<<256, 256, 0, stream>>>(plog, bro, out);
}

// Round 7
// 1512.314 us; speedup vs baseline: 2.0747x; 1.2807x over previous
//
#include <hip/hip_runtime.h>
#include <cstdint>

#define H_DIM 512
#define B_DIM 256
#define T_DIM 256

typedef __bf16 bf16x8 __attribute__((ext_vector_type(8)));
typedef __bf16 bf16x4 __attribute__((ext_vector_type(4)));
typedef float  f32x4  __attribute__((ext_vector_type(4)));
typedef unsigned long long ull;

__device__ __forceinline__ void cvt_split(float4 a, float4 b, bf16x8& h, bf16x8& lo) {
  const float v[8] = {a.x, a.y, a.z, a.w, b.x, b.y, b.z, b.w};
#pragma unroll
  for (int j = 0; j < 8; ++j) {
    h[j]  = (__bf16)v[j];
    lo[j] = (__bf16)(v[j] - (float)h[j]);
  }
}

__device__ __forceinline__ bf16x8 cvt8(const float* p) {
  const float4 s0 = *(const float4*)p;
  const float4 s1 = *(const float4*)(p + 4);
  bf16x8 v;
  v[0] = (__bf16)s0.x; v[1] = (__bf16)s0.y; v[2] = (__bf16)s0.z; v[3] = (__bf16)s0.w;
  v[4] = (__bf16)s1.x; v[5] = (__bf16)s1.y; v[6] = (__bf16)s1.z; v[7] = (__bf16)s1.w;
  return v;
}

// =====================================================================
// K1: Ux[(t*256+b)*512 + i] = sum_k x[b][t][k]*U[i][k] + bias[i]
// bf16 split-MFMA (xh@Uh + xh@Ul + xl@Uh ~ f32 accurate), f32 output.
// =====================================================================
__global__ __launch_bounds__(256, 2) void k1_ux(const float* __restrict__ x,
                                                const float* __restrict__ U,
                                                const float* __restrict__ bias,
                                                float* __restrict__ Ux) {
  __shared__ __align__(16) __bf16 XH[128][40];
  __shared__ __align__(16) __bf16 XL[128][40];
  __shared__ __align__(16) __bf16 UH[128][40];
  __shared__ __align__(16) __bf16 UL[128][40];

  const int tid = threadIdx.x;
  const int l   = tid & 63;
  const int w   = tid >> 6;
  const int wm  = w >> 1;
  const int wn  = w & 1;
  const int r0  = blockIdx.x * 128;
  const int i0  = blockIdx.y * 128;
  const int t   = r0 >> 8;
  const int b0  = r0 & 255;

  const int srow  = tid >> 1;
  const int shalf = tid & 1;

  f32x4 acc[4][4];
#pragma unroll
  for (int mi = 0; mi < 4; ++mi)
#pragma unroll
    for (int ni = 0; ni < 4; ++ni) acc[mi][ni] = (f32x4){0.f, 0.f, 0.f, 0.f};

  const int lrow = l & 15;
  const int lgrn = (l >> 4) * 8;

  for (int k0 = 0; k0 < H_DIM; k0 += 32) {
    __syncthreads();
    {
      const float* xsrc = x + ((size_t)(b0 + srow) * T_DIM + t) * H_DIM + k0 + shalf * 16;
      const float* usrc = U + (size_t)(i0 + srow) * H_DIM + k0 + shalf * 16;
      bf16x8 h0, l0, h1, l1;
      cvt_split(*(const float4*)xsrc, *(const float4*)(xsrc + 4), h0, l0);
      cvt_split(*(const float4*)(xsrc + 8), *(const float4*)(xsrc + 12), h1, l1);
      *(bf16x8*)&XH[srow][shalf * 16]     = h0;
      *(bf16x8*)&XH[srow][shalf * 16 + 8] = h1;
      *(bf16x8*)&XL[srow][shalf * 16]     = l0;
      *(bf16x8*)&XL[srow][shalf * 16 + 8] = l1;
      cvt_split(*(const float4*)usrc, *(const float4*)(usrc + 4), h0, l0);
      cvt_split(*(const float4*)(usrc + 8), *(const float4*)(usrc + 12), h1, l1);
      *(bf16x8*)&UH[srow][shalf * 16]     = h0;
      *(bf16x8*)&UH[srow][shalf * 16 + 8] = h1;
      *(bf16x8*)&UL[srow][shalf * 16]     = l0;
      *(bf16x8*)&UL[srow][shalf * 16 + 8] = l1;
    }
    __syncthreads();

    bf16x8 ah[4], al[4], bh[4], blo[4];
#pragma unroll
    for (int mi = 0; mi < 4; ++mi) {
      ah[mi] = *(const bf16x8*)&XH[wm * 64 + mi * 16 + lrow][lgrn];
      al[mi] = *(const bf16x8*)&XL[wm * 64 + mi * 16 + lrow][lgrn];
    }
#pragma unroll
    for (int ni = 0; ni < 4; ++ni) {
      bh[ni]  = *(const bf16x8*)&UH[wn * 64 + ni * 16 + lrow][lgrn];
      blo[ni] = *(const bf16x8*)&UL[wn * 64 + ni * 16 + lrow][lgrn];
    }
#pragma unroll
    for (int mi = 0; mi < 4; ++mi)
#pragma unroll
      for (int ni = 0; ni < 4; ++ni) {
        acc[mi][ni] = __builtin_amdgcn_mfma_f32_16x16x32_bf16(ah[mi], bh[ni],  acc[mi][ni], 0, 0, 0);
        acc[mi][ni] = __builtin_amdgcn_mfma_f32_16x16x32_bf16(ah[mi], blo[ni], acc[mi][ni], 0, 0, 0);
        acc[mi][ni] = __builtin_amdgcn_mfma_f32_16x16x32_bf16(al[mi], bh[ni],  acc[mi][ni], 0, 0, 0);
      }
  }

  float bv[4];
#pragma unroll
  for (int ni = 0; ni < 4; ++ni) bv[ni] = bias[i0 + wn * 64 + ni * 16 + lrow];
#pragma unroll
  for (int mi = 0; mi < 4; ++mi)
#pragma unroll
    for (int ni = 0; ni < 4; ++ni) {
      const int col = i0 + wn * 64 + ni * 16 + lrow;
      const int row = r0 + wm * 64 + mi * 16 + (l >> 4) * 4;
#pragma unroll
      for (int r = 0; r < 4; ++r)
        Ux[(size_t)(row + r) * H_DIM + col] = acc[mi][ni][r] + bv[ni];
    }
}

// =====================================================================
// K2: scan. 64 blocks x 512 threads. bid = slice*8 + g.
//   Swapped-operand MFMA: C'[f][b] = [W;A] . y^T.  Wave (bh, fq) owns a
//   16-feature x 16-batch tile; W/A rows are operand A (feature = l&15),
//   y is operand B (batch col = l&15) -> OUTPUT lane holds 4 consecutive
//   features x 1 batch = exactly one 8B chunk of the next step's y-frag.
//   ybuf tile layout (per 16-batch tile, 16 KB):
//     byte(row=batch, f) = ks*1024 + jh*512 + (m*16+row)*8 + jl*2
//     (f = ks*32 + m*8 + jh*4 + jl)
//   -> consumer frag ks: two 8B loads at l*8 / l*8+512 (512B coalesced)
//   -> producer: ONE 8B store per lane (4 x 128B runs, full lines).
//   No LDS, no __syncthreads. Sync: per-wave flags over the 32 waves
//   sharing (g, bh); relaxed agent atomics only.
// =====================================================================
__global__ __launch_bounds__(512, 1) void k2_scan(const float* __restrict__ W,
                                                  const float* __restrict__ Amat,
                                                  const float* __restrict__ y0,
                                                  const float* __restrict__ Ux,
                                                  const float* __restrict__ Wro,
                                                  __bf16* __restrict__ ybuf,      // 2 x 131072 bf16 (tile order)
                                                  float* __restrict__ plog,       // [T][32][B]
                                                  unsigned int* __restrict__ flags) {  // [8][2][32]
  const int tid   = threadIdx.x;
  const int g     = blockIdx.x & 7;
  const int slice = blockIdx.x >> 3;
  const int fbase = slice * 64;

  const int l   = tid & 63;
  const int w   = tid >> 6;      // 0..7
  const int bh  = w & 1;         // batch half (16)
  const int fq  = w >> 1;        // feature 16-group within 64-slice
  const int l15 = l & 15;
  const int lhi = l >> 4;        // 0..3

  const int b_loc  = bh * 16 + l15;             // epilogue batch (C col) & frag row
  const int b_glob = g * 32 + b_loc;
  const int f0     = fbase + fq * 16 + lhi * 4; // lane's 4 output features (C rows)
  const int frow   = fbase + fq * 16 + l15;     // lane's W/A frag row (operand A)

  // ---- own f32 state: y[b_glob][f0..f0+3] ----
  float4 yst4 = *(const float4*)(y0 + (size_t)b_glob * H_DIM + f0);
  float yst[4] = {yst4.x, yst4.y, yst4.z, yst4.w};
  const float4 wrov = *(const float4*)(Wro + f0);

  // ---- W/A operand-A frags (row = frow, k = ks*32 + lhi*8 + j) ----
  bf16x8 aW[16], aA[16];
#pragma unroll
  for (int ks = 0; ks < 16; ++ks) {
    aW[ks] = cvt8(W    + (size_t)frow * H_DIM + ks * 32 + lhi * 8);
    aA[ks] = cvt8(Amat + (size_t)frow * H_DIM + ks * 32 + lhi * 8);
  }

  // ---- store addressing (from f0, within own (g,bh) tile) ----
  const size_t tix  = (size_t)(g * 2 + bh);
  const int ks_s = f0 >> 5;
  const int m_s  = (f0 >> 3) & 3;
  const int jh_s = (f0 >> 2) & 1;
  const size_t st_off = tix * 16384 + (size_t)ks_s * 1024 + (size_t)jh_s * 512
                      + (size_t)(m_s * 16 + l15) * 8;

  for (int t = 0; t < T_DIM; ++t) {
    // input-path term: issue before the wait (latency hides under it)
    const float4 uxv = *(const float4*)(Ux + ((size_t)t * B_DIM + b_glob) * H_DIM + f0);

    // ---- wait: the 32 waves of (g, bh) published y_t ----
    if (t > 0) {
      const unsigned target = (unsigned)t;
      const unsigned int* fp = flags + g * 64 + bh * 32 + l;
      for (;;) {
        unsigned v = target;
        if (l < 32)
          v = __hip_atomic_load(fp, __ATOMIC_RELAXED, __HIP_MEMORY_SCOPE_AGENT);
        if (__all(v >= target)) break;
        __builtin_amdgcn_s_sleep(1);
      }
      asm volatile("" ::: "memory");
    }

    // ---- y operand-B frags: 2 coalesced 8B loads per ks ----
    bf16x8 bv[16];
    if (t == 0) {
      const float* pa = y0 + (size_t)(g * 32 + bh * 16 + l15) * H_DIM + lhi * 8;
#pragma unroll
      for (int ks = 0; ks < 16; ++ks) bv[ks] = cvt8(pa + ks * 32);
    } else {
      const char* abase = (const char*)ybuf + (size_t)(t & 1) * 262144
                        + tix * 16384 + (size_t)l * 8;
#pragma unroll
      for (int ks = 0; ks < 16; ++ks) {
        ull u2[2];
        u2[0] = __hip_atomic_load((const ull*)(abase + ks * 1024),
                                  __ATOMIC_RELAXED, __HIP_MEMORY_SCOPE_AGENT);
        u2[1] = __hip_atomic_load((const ull*)(abase + ks * 1024 + 512),
                                  __ATOMIC_RELAXED, __HIP_MEMORY_SCOPE_AGENT);
        __builtin_memcpy(&bv[ks], u2, 16);
      }
    }

    // ---- MFMA: C'[f][b] for both matvecs, K=512, 2-way split chains ----
    f32x4 accP0 = {0.f, 0.f, 0.f, 0.f}, accP1 = {0.f, 0.f, 0.f, 0.f};
    f32x4 accG0 = {0.f, 0.f, 0.f, 0.f}, accG1 = {0.f, 0.f, 0.f, 0.f};
#pragma unroll
    for (int ks = 0; ks < 16; ks += 2) {
      accP0 = __builtin_amdgcn_mfma_f32_16x16x32_bf16(aW[ks],     bv[ks],     accP0, 0, 0, 0);
      accG0 = __builtin_amdgcn_mfma_f32_16x16x32_bf16(aA[ks],     bv[ks],     accG0, 0, 0, 0);
      accP1 = __builtin_amdgcn_mfma_f32_16x16x32_bf16(aW[ks + 1], bv[ks + 1], accP1, 0, 0, 0);
      accG1 = __builtin_amdgcn_mfma_f32_16x16x32_bf16(aA[ks + 1], bv[ks + 1], accG1, 0, 0, 0);
    }

    // ---- register epilogue: 4 features x 1 batch per lane ----
    float s = 0.0f;
    bf16x4 pk;
    const float uxa[4] = {uxv.x, uxv.y, uxv.z, uxv.w};
    const float wra[4] = {wrov.x, wrov.y, wrov.z, wrov.w};
#pragma unroll
    for (int r = 0; r < 4; ++r) {
      const float pre  = accP0[r] + accP1[r] + uxa[r];
      const float gate = 1.0f / (1.0f + expf(-(accG0[r] + accG1[r])));
      const float yn   = yst[r] + 0.1f * tanhf(pre) * gate;
      yst[r] = yn;
      pk[r] = (__bf16)yn;
      s += yn * wra[r];
    }
    ull pv;
    __builtin_memcpy(&pv, &pk, 8);
    ull* dst = (ull*)((char*)ybuf + (size_t)((t + 1) & 1) * 262144 + st_off);
    __hip_atomic_store(dst, pv, __ATOMIC_RELAXED, __HIP_MEMORY_SCOPE_AGENT);

    // readout partial: reduce over the 4 lhi feature-groups
    s += __shfl_xor(s, 16, 64);
    s += __shfl_xor(s, 32, 64);
    if (l < 16)
      plog[((size_t)t * 32 + slice * 4 + fq) * B_DIM + g * 32 + bh * 16 + l] = s;

    // ---- per-wave release: drain own stores, publish wave flag ----
    asm volatile("s_waitcnt vmcnt(0)" ::: "memory");
    if (l == 0)
      __hip_atomic_store(flags + g * 64 + bh * 32 + slice * 4 + fq, (unsigned)(t + 1),
                         __ATOMIC_RELAXED, __HIP_MEMORY_SCOPE_AGENT);
  }
}

// =====================================================================
// K3: out[b][t] = bro + sum_{c<32} plog[t][c][b]
// =====================================================================
__global__ __launch_bounds__(256) void k3_out(const float* __restrict__ plog,
                                              const float* __restrict__ bro,
                                              float* __restrict__ out) {
  const int t = blockIdx.x;
  const int b = threadIdx.x;
  float s = bro[0];
#pragma unroll
  for (int col = 0; col < 32; ++col)
    s += plog[((size_t)t * 32 + col) * B_DIM + b];
  out[(size_t)b * T_DIM + t] = s;
}

// =====================================================================
extern "C" void kernel_launch(void* const* d_in, const int* in_sizes, int n_in,
                              void* d_out, int out_size, void* d_ws, size_t ws_size,
                              hipStream_t stream) {
  const float* x   = (const float*)d_in[0];
  const float* y0  = (const float*)d_in[1];
  const float* W   = (const float*)d_in[2];
  const float* U   = (const float*)d_in[3];
  const float* b   = (const float*)d_in[4];
  const float* A   = (const float*)d_in[5];
  const float* Wro = (const float*)d_in[6];
  const float* bro = (const float*)d_in[7];
  float* out = (float*)d_out;

  float* ws = (float*)d_ws;
  float* Ux = ws;                                               // 33,554,432 f32
  __bf16* ybuf = (__bf16*)(ws + (size_t)T_DIM * B_DIM * H_DIM); // 262,144 bf16 (tile order)
  float* plog = ws + (size_t)T_DIM * B_DIM * H_DIM + 131072;    // 2,097,152 f32
  unsigned int* flags = (unsigned int*)(plog + (size_t)T_DIM * 32 * B_DIM);  // 512 u32

  (void)in_sizes; (void)n_in; (void)out_size; (void)ws_size;

  hipMemsetAsync(flags, 0, 512 * sizeof(unsigned int), stream);

  dim3 g1(512, 4);
  k1_ux<<<g1, 256, 0, stream>>>(x, U, b, Ux);
  k2_scan<<<64, 512, 0, stream>>>(W, A, y0, Ux, Wro, ybuf, plog, flags);
  k3_out<<<256, 256, 0, stream>>>(plog, bro, out);
}